// Round 2
// baseline (170.324 us; speedup 1.0000x reference)
//
#include <hip/hip_runtime.h>
#include <cstdint>
#include <cstddef>

#define U   32
#define DM  2560
#define DI  5120
#define DS  16
#define RNK 160
#define XD  192   // RNK + 2*DS

// ---------------------------------------------------------------------------
// K1: dual skinny GEMM  xs = xb @ w_in_ssm, res = xb @ w_in_mlp
// grid (80 ntiles, 8 kc, 2 z), block 256 = 4 waves x 64 cols.
// Each wave owns an 80-row K-slice; LDS reduce; partials to ws (no atomics).
// ---------------------------------------------------------------------------
__global__ __launch_bounds__(256) void k1_dualgemm(
    const float* __restrict__ x,
    const float* __restrict__ w_ssm,
    const float* __restrict__ w_mlp,
    float* __restrict__ part)
{
  __shared__ union { float xt[U][320]; float red[4][64][33]; } sh;
  const int z  = blockIdx.z;
  const int kc = blockIdx.y;
  const int k0 = kc * 320;
  const float* W = z ? w_mlp : w_ssm;

  // stage x[32][320] K-panel
  for (int i4 = threadIdx.x; i4 < U * 80; i4 += 256) {
    int u = i4 / 80, k4 = i4 - u * 80;
    *(float4*)&sh.xt[u][k4 * 4] = *(const float4*)&x[u * DM + k0 + k4 * 4];
  }
  __syncthreads();

  const int c = threadIdx.x & 63, s = threadIdx.x >> 6;
  const int col = blockIdx.x * 64 + c;
  const float* Wp = W + (size_t)(k0 + s * 80) * DI + col;

  float acc[U];
#pragma unroll
  for (int u = 0; u < U; ++u) acc[u] = 0.f;

  for (int kk = 0; kk < 80; kk += 4) {
    float w0 = Wp[(size_t)(kk + 0) * DI];
    float w1 = Wp[(size_t)(kk + 1) * DI];
    float w2 = Wp[(size_t)(kk + 2) * DI];
    float w3 = Wp[(size_t)(kk + 3) * DI];
#pragma unroll
    for (int u = 0; u < U; ++u) {
      float4 xv = *(const float4*)&sh.xt[u][s * 80 + kk];  // wave-uniform bcast
      acc[u] = fmaf(xv.x, w0, acc[u]);
      acc[u] = fmaf(xv.y, w1, acc[u]);
      acc[u] = fmaf(xv.z, w2, acc[u]);
      acc[u] = fmaf(xv.w, w3, acc[u]);
    }
  }

  __syncthreads();           // done reading xt
#pragma unroll
  for (int u = 0; u < U; ++u) sh.red[s][c][u] = acc[u];   // stride33: no conflict
  __syncthreads();

  for (int p = threadIdx.x; p < 64 * U; p += 256) {
    int cc = p & 63, u = p >> 6;
    float v = sh.red[0][cc][u] + sh.red[1][cc][u] + sh.red[2][cc][u] + sh.red[3][cc][u];
    part[((size_t)(z * 8 + kc) * U + u) * DI + blockIdx.x * 64 + cc] = v;
  }
}

// ---------------------------------------------------------------------------
// K2a: reduce K1 partials (8 each) + conv + silu.  grid 640, block 256.
// ---------------------------------------------------------------------------
__global__ __launch_bounds__(256) void k2a_convsilu(
    const float* __restrict__ part,
    const float* __restrict__ cs1, const float* __restrict__ cs2,
    const float* __restrict__ cs3,
    const float* __restrict__ cw,  const float* __restrict__ cb,
    float* __restrict__ c_ws, float* __restrict__ res_ws)
{
  const int i = blockIdx.x * 256 + threadIdx.x;   // [0, U*DI)
  const int d = i % DI;
  float xs = 0.f, rs = 0.f;
#pragma unroll
  for (int kc = 0; kc < 8; ++kc) {
    xs += part[((size_t)kc * U      + (i / DI)) * DI + d];
    rs += part[((size_t)(8 + kc) * U + (i / DI)) * DI + d];
  }
  float cc = cs1[i] * cw[d] + cs2[i] * cw[DI + d] + cs3[i] * cw[2 * DI + d]
           + xs * cw[3 * DI + d] + cb[d];
  cc = cc / (1.f + __expf(-cc));                  // silu
  c_ws[i]   = cc;
  res_ws[i] = rs;
}

// ---------------------------------------------------------------------------
// K2b: x_dbl = c @ x_proj_w (32x5120 @ 5120x192).  grid (3, 16), block 256.
// Slice-reduce in LDS, then one atomicAdd per output per block (16/addr).
// ---------------------------------------------------------------------------
__global__ __launch_bounds__(256) void k2b_xproj(
    const float* __restrict__ c_ws,
    const float* __restrict__ xpw,
    float* __restrict__ x_dbl)
{
  __shared__ union { float ct[U][320]; float red[4][64][33]; } sh;
  const int k0 = blockIdx.y * 320;

  for (int i4 = threadIdx.x; i4 < U * 80; i4 += 256) {
    int u = i4 / 80, k4 = i4 - u * 80;
    *(float4*)&sh.ct[u][k4 * 4] = *(const float4*)&c_ws[u * DI + k0 + k4 * 4];
  }
  __syncthreads();

  const int c = threadIdx.x & 63, s = threadIdx.x >> 6;
  const int col = blockIdx.x * 64 + c;              // 0..191
  const float* Wp = xpw + (size_t)(k0 + s * 80) * XD + col;

  float acc[U];
#pragma unroll
  for (int u = 0; u < U; ++u) acc[u] = 0.f;

  for (int kk = 0; kk < 80; kk += 4) {
    float w0 = Wp[(size_t)(kk + 0) * XD];
    float w1 = Wp[(size_t)(kk + 1) * XD];
    float w2 = Wp[(size_t)(kk + 2) * XD];
    float w3 = Wp[(size_t)(kk + 3) * XD];
#pragma unroll
    for (int u = 0; u < U; ++u) {
      float4 cv = *(const float4*)&sh.ct[u][s * 80 + kk];
      acc[u] = fmaf(cv.x, w0, acc[u]);
      acc[u] = fmaf(cv.y, w1, acc[u]);
      acc[u] = fmaf(cv.z, w2, acc[u]);
      acc[u] = fmaf(cv.w, w3, acc[u]);
    }
  }

  __syncthreads();
#pragma unroll
  for (int u = 0; u < U; ++u) sh.red[s][c][u] = acc[u];
  __syncthreads();

  for (int p = threadIdx.x; p < 64 * U; p += 256) {
    int cc = p & 63, u = p >> 6;
    float v = sh.red[0][cc][u] + sh.red[1][cc][u] + sh.red[2][cc][u] + sh.red[3][cc][u];
    atomicAdd(&x_dbl[u * XD + blockIdx.x * 64 + cc], v);
  }
}

// ---------------------------------------------------------------------------
// K3a: dt = softplus(x_dbl[:, :160] @ dt_proj_w + b).  grid 80, block 256.
// ---------------------------------------------------------------------------
__global__ __launch_bounds__(256) void k3a_dt(
    const float* __restrict__ x_dbl,
    const float* __restrict__ dpw, const float* __restrict__ dpb,
    float* __restrict__ dt_ws)
{
  __shared__ union { float xt[U][160]; float red[4][64][33]; } sh;

  for (int i4 = threadIdx.x; i4 < U * 40; i4 += 256) {
    int u = i4 / 40, r4 = i4 - u * 40;
    *(float4*)&sh.xt[u][r4 * 4] = *(const float4*)&x_dbl[u * XD + r4 * 4];
  }
  __syncthreads();

  const int c = threadIdx.x & 63, s = threadIdx.x >> 6;
  const int d = blockIdx.x * 64 + c;
  const float* Wp = dpw + (size_t)(s * 40) * DI + d;

  float acc[U];
#pragma unroll
  for (int u = 0; u < U; ++u) acc[u] = 0.f;

  for (int rr = 0; rr < 40; rr += 4) {
    float w0 = Wp[(size_t)(rr + 0) * DI];
    float w1 = Wp[(size_t)(rr + 1) * DI];
    float w2 = Wp[(size_t)(rr + 2) * DI];
    float w3 = Wp[(size_t)(rr + 3) * DI];
#pragma unroll
    for (int u = 0; u < U; ++u) {
      float4 xv = *(const float4*)&sh.xt[u][s * 40 + rr];
      acc[u] = fmaf(xv.x, w0, acc[u]);
      acc[u] = fmaf(xv.y, w1, acc[u]);
      acc[u] = fmaf(xv.z, w2, acc[u]);
      acc[u] = fmaf(xv.w, w3, acc[u]);
    }
  }

  __syncthreads();
#pragma unroll
  for (int u = 0; u < U; ++u) sh.red[s][c][u] = acc[u];
  __syncthreads();

  for (int p = threadIdx.x; p < 64 * U; p += 256) {
    int cc = p & 63, u = p >> 6;
    int dg = blockIdx.x * 64 + cc;
    float pre = sh.red[0][cc][u] + sh.red[1][cc][u] + sh.red[2][cc][u] + sh.red[3][cc][u]
              + dpb[dg];
    float dt = fmaxf(pre, 0.f) + log1pf(expf(-fabsf(pre)));   // softplus
    dt_ws[u * DI + dg] = dt;
  }
}

// ---------------------------------------------------------------------------
// K3b: elementwise SSM update + y = einsum + D*c, yr = y*res.  grid 640.
// ---------------------------------------------------------------------------
__global__ __launch_bounds__(256) void k3b_ssm(
    const float* __restrict__ x_dbl,
    const float* __restrict__ alog, const float* __restrict__ Dp,
    const float* __restrict__ ssm,
    const float* __restrict__ dt_ws,
    const float* __restrict__ c_ws, const float* __restrict__ res_ws,
    float* __restrict__ yr)
{
  const int i = blockIdx.x * 256 + threadIdx.x;   // [0, U*DI)
  const int u = i / DI, d = i - u * DI;

  const float dt = dt_ws[i];
  const float cv = c_ws[i];
  const float rv = res_ws[i];
  const float Dv = Dp[d];
  const float dtc = dt * cv;

  float4 B[4], C[4];
#pragma unroll
  for (int q = 0; q < 4; ++q) {
    B[q] = *(const float4*)&x_dbl[u * XD + RNK + q * 4];          // wave-uniform
    C[q] = *(const float4*)&x_dbl[u * XD + RNK + DS + q * 4];
  }

  const float* st = ssm + ((size_t)u * DI + d) * DS;
  float y = 0.f;
#pragma unroll
  for (int q = 0; q < 4; ++q) {
    float4 al = *(const float4*)&alog[d * DS + q * 4];
    float4 sv = *(const float4*)&st[q * 4];
    y += (sv.x * __expf(dt * -__expf(al.x)) + dtc * B[q].x) * C[q].x;
    y += (sv.y * __expf(dt * -__expf(al.y)) + dtc * B[q].y) * C[q].y;
    y += (sv.z * __expf(dt * -__expf(al.z)) + dtc * B[q].z) * C[q].z;
    y += (sv.w * __expf(dt * -__expf(al.w)) + dtc * B[q].w) * C[q].w;
  }
  y = fmaf(Dv, cv, y);
  yr[i] = y * rv;
}

// ---------------------------------------------------------------------------
// K4: out = yr @ w_out (32x5120 @ 5120x2560).  grid (40, 16), block 256.
// Same slice-reduce structure; partials to ws.
// ---------------------------------------------------------------------------
__global__ __launch_bounds__(256) void k4_outgemm(
    const float* __restrict__ yr,
    const float* __restrict__ wout,
    float* __restrict__ part4)
{
  __shared__ union { float yt[U][320]; float red[4][64][33]; } sh;
  const int kc = blockIdx.y;
  const int k0 = kc * 320;

  for (int i4 = threadIdx.x; i4 < U * 80; i4 += 256) {
    int u = i4 / 80, k4 = i4 - u * 80;
    *(float4*)&sh.yt[u][k4 * 4] = *(const float4*)&yr[u * DI + k0 + k4 * 4];
  }
  __syncthreads();

  const int c = threadIdx.x & 63, s = threadIdx.x >> 6;
  const int col = blockIdx.x * 64 + c;
  const float* Wp = wout + (size_t)(k0 + s * 80) * DM + col;

  float acc[U];
#pragma unroll
  for (int u = 0; u < U; ++u) acc[u] = 0.f;

  for (int kk = 0; kk < 80; kk += 4) {
    float w0 = Wp[(size_t)(kk + 0) * DM];
    float w1 = Wp[(size_t)(kk + 1) * DM];
    float w2 = Wp[(size_t)(kk + 2) * DM];
    float w3 = Wp[(size_t)(kk + 3) * DM];
#pragma unroll
    for (int u = 0; u < U; ++u) {
      float4 yv = *(const float4*)&sh.yt[u][s * 80 + kk];
      acc[u] = fmaf(yv.x, w0, acc[u]);
      acc[u] = fmaf(yv.y, w1, acc[u]);
      acc[u] = fmaf(yv.z, w2, acc[u]);
      acc[u] = fmaf(yv.w, w3, acc[u]);
    }
  }

  __syncthreads();
#pragma unroll
  for (int u = 0; u < U; ++u) sh.red[s][c][u] = acc[u];
  __syncthreads();

  for (int p = threadIdx.x; p < 64 * U; p += 256) {
    int cc = p & 63, u = p >> 6;
    float v = sh.red[0][cc][u] + sh.red[1][cc][u] + sh.red[2][cc][u] + sh.red[3][cc][u];
    part4[((size_t)kc * U + u) * DM + blockIdx.x * 64 + cc] = v;
  }
}

// ---------------------------------------------------------------------------
// K5: out = sum of 16 K4 partials.  grid 320, block 256.
// ---------------------------------------------------------------------------
__global__ __launch_bounds__(256) void k5_reduce(
    const float* __restrict__ part4,
    float* __restrict__ out)
{
  const int i = blockIdx.x * 256 + threadIdx.x;   // [0, U*DM)
  const int u = i / DM, d = i - u * DM;
  float v = 0.f;
#pragma unroll
  for (int kc = 0; kc < 16; ++kc) v += part4[((size_t)kc * U + u) * DM + d];
  out[i] = v;
}

// ---------------------------------------------------------------------------
extern "C" void kernel_launch(void* const* d_in, const int* in_sizes, int n_in,
                              void* d_out, int out_size, void* d_ws, size_t ws_size,
                              hipStream_t stream)
{
  const float* x    = (const float*)d_in[0];
  const float* wssm = (const float*)d_in[1];
  const float* wmlp = (const float*)d_in[2];
  const float* wout = (const float*)d_in[3];
  const float* cw   = (const float*)d_in[4];
  const float* cb   = (const float*)d_in[5];
  const float* cs1  = (const float*)d_in[6];
  const float* cs2  = (const float*)d_in[7];
  const float* cs3  = (const float*)d_in[8];
  const float* xpw  = (const float*)d_in[9];
  const float* dpw  = (const float*)d_in[10];
  const float* dpb  = (const float*)d_in[11];
  const float* alog = (const float*)d_in[12];
  const float* Dp   = (const float*)d_in[13];
  const float* ssm  = (const float*)d_in[14];
  float* out = (float*)d_out;
  float* ws  = (float*)d_ws;

  float* part1  = ws;                               // 2*8*32*5120 = 2,621,440
  float* part4  = part1 + (size_t)2 * 8 * U * DI;   // 16*32*2560 = 1,310,720
  float* c_ws   = part4 + (size_t)16 * U * DM;
  float* res_ws = c_ws   + (size_t)U * DI;
  float* dt_ws  = res_ws + (size_t)U * DI;
  float* yrb    = dt_ws  + (size_t)U * DI;
  float* x_dbl  = yrb    + (size_t)U * DI;          // 6144 floats

  hipMemsetAsync(x_dbl, 0, (size_t)U * XD * sizeof(float), stream);

  k1_dualgemm<<<dim3(80, 8, 2), 256, 0, stream>>>(x, wssm, wmlp, part1);
  k2a_convsilu<<<640, 256, 0, stream>>>(part1, cs1, cs2, cs3, cw, cb, c_ws, res_ws);
  k2b_xproj<<<dim3(3, 16), 256, 0, stream>>>(c_ws, xpw, x_dbl);
  k3a_dt<<<80, 256, 0, stream>>>(x_dbl, dpw, dpb, dt_ws);
  k3b_ssm<<<640, 256, 0, stream>>>(x_dbl, alog, Dp, ssm, dt_ws, c_ws, res_ws, yrb);
  k4_outgemm<<<dim3(40, 16), 256, 0, stream>>>(yrb, wout, part4);
  k5_reduce<<<320, 256, 0, stream>>>(part4, out);
}

// Round 4
// 143.799 us; speedup vs baseline: 1.1845x; 1.1845x over previous
//
#include <hip/hip_runtime.h>
#include <cstdint>
#include <cstddef>

#define U   32
#define DM  2560
#define DI  5120
#define DS  16
#define RNK 160
#define XD  192   // RNK + 2*DS

__device__ __forceinline__ void fma4(float4& a, float xs, const float4& wv) {
  a.x = fmaf(xs, wv.x, a.x);
  a.y = fmaf(xs, wv.y, a.y);
  a.z = fmaf(xs, wv.z, a.z);
  a.w = fmaf(xs, wv.w, a.w);
}

__device__ __forceinline__ float f4c(const float4& v, int cc) {
  return cc == 0 ? v.x : cc == 1 ? v.y : cc == 2 ? v.z : v.w;   // cc literal after unroll
}

// ---------------------------------------------------------------------------
// Skinny GEMM template: out_part[kc][32][LDW-cols] += A[32][K] @ W[K][LDW]
// block 256 = 4 waves; wave s owns K-slice of S rows; thread owns 4 cols
// (float4 weight loads). LDS x-panel broadcast: 1 B LDS per FMA.
// grid (LDW/256, K/(4S), nz). Cross-wave reduce via LDS, 4 passes.
// ---------------------------------------------------------------------------
template<int LDW, int S>
__global__ __launch_bounds__(256, 2) void skinny_gemm(
    const float* __restrict__ A, int lda,
    const float* __restrict__ W0, const float* __restrict__ W1,
    float* __restrict__ part)
{
  constexpr int CHUNK = 4 * S;
  __shared__ union { float xt[U][CHUNK]; float red[4][64][33]; } sh;
  const int colt = blockIdx.x, kc = blockIdx.y, z = blockIdx.z;
  const float* W = z ? W1 : W0;
  const int k0 = kc * CHUNK;

  for (int i4 = threadIdx.x; i4 < U * (CHUNK / 4); i4 += 256) {
    int u = i4 / (CHUNK / 4), g = i4 - u * (CHUNK / 4);
    *(float4*)&sh.xt[u][g * 4] = *(const float4*)&A[u * lda + k0 + g * 4];
  }
  __syncthreads();

  const int lane = threadIdx.x & 63, s = threadIdx.x >> 6;
  const int col0 = colt * 256 + lane * 4;
  const float* Wp = W + (size_t)(k0 + s * S) * LDW + col0;

  float4 acc[U];
#pragma unroll
  for (int u = 0; u < U; ++u) acc[u] = make_float4(0.f, 0.f, 0.f, 0.f);

  // register double-buffer of 4 weight rows
  float4 wa0 = *(const float4*)(Wp + (size_t)0 * LDW);
  float4 wa1 = *(const float4*)(Wp + (size_t)1 * LDW);
  float4 wa2 = *(const float4*)(Wp + (size_t)2 * LDW);
  float4 wa3 = *(const float4*)(Wp + (size_t)3 * LDW);

  for (int kk = 0; kk < S; kk += 4) {
    const int kn = (kk + 4 < S) ? kk + 4 : kk;     // clamp: last prefetch re-reads
    float4 wb0 = *(const float4*)(Wp + (size_t)(kn + 0) * LDW);
    float4 wb1 = *(const float4*)(Wp + (size_t)(kn + 1) * LDW);
    float4 wb2 = *(const float4*)(Wp + (size_t)(kn + 2) * LDW);
    float4 wb3 = *(const float4*)(Wp + (size_t)(kn + 3) * LDW);
#pragma unroll
    for (int u = 0; u < U; ++u) {
      float4 xv = *(const float4*)&sh.xt[u][s * S + kk];   // wave-uniform bcast
      fma4(acc[u], xv.x, wa0);
      fma4(acc[u], xv.y, wa1);
      fma4(acc[u], xv.z, wa2);
      fma4(acc[u], xv.w, wa3);
    }
    wa0 = wb0; wa1 = wb1; wa2 = wb2; wa3 = wb3;
  }

  const size_t zoff = (size_t)z * gridDim.y * U * LDW;
#pragma unroll
  for (int cc = 0; cc < 4; ++cc) {
    __syncthreads();
#pragma unroll
    for (int u = 0; u < U; ++u) sh.red[s][lane][u] = f4c(acc[u], cc);
    __syncthreads();
    for (int p = threadIdx.x; p < 64 * U; p += 256) {
      int l = p & 63, u = p >> 6;
      float v = sh.red[0][l][u] + sh.red[1][l][u] + sh.red[2][l][u] + sh.red[3][l][u];
      part[zoff + ((size_t)kc * U + u) * LDW + colt * 256 + l * 4 + cc] = v;
    }
  }
}

// ---------------------------------------------------------------------------
// K2a: reduce K1 partials (16 per z) + conv + silu.  grid 640, block 256.
// ---------------------------------------------------------------------------
__global__ __launch_bounds__(256) void k2a_convsilu(
    const float* __restrict__ part,
    const float* __restrict__ cs1, const float* __restrict__ cs2,
    const float* __restrict__ cs3,
    const float* __restrict__ cw,  const float* __restrict__ cb,
    float* __restrict__ c_ws, float* __restrict__ res_ws)
{
  const int i = blockIdx.x * 256 + threadIdx.x;   // [0, U*DI)
  const int u = i / DI, d = i - u * DI;
  float xs = 0.f, rs = 0.f;
#pragma unroll
  for (int kc = 0; kc < 16; ++kc) {
    xs += part[((size_t)kc * U        + u) * DI + d];
    rs += part[((size_t)(16 + kc) * U + u) * DI + d];
  }
  float cc = cs1[i] * cw[d] + cs2[i] * cw[DI + d] + cs3[i] * cw[2 * DI + d]
           + xs * cw[3 * DI + d] + cb[d];
  cc = cc / (1.f + __expf(-cc));                  // silu
  c_ws[i]   = cc;
  res_ws[i] = rs;
}

// ---------------------------------------------------------------------------
// K2b: x_dbl = c @ x_proj_w (32x5120 @ 5120x192).  grid (3, 16), block 256.
// ---------------------------------------------------------------------------
__global__ __launch_bounds__(256) void k2b_xproj(
    const float* __restrict__ c_ws,
    const float* __restrict__ xpw,
    float* __restrict__ x_dbl)
{
  __shared__ union { float ct[U][320]; float red[4][64][33]; } sh;
  const int k0 = blockIdx.y * 320;

  for (int i4 = threadIdx.x; i4 < U * 80; i4 += 256) {
    int u = i4 / 80, k4 = i4 - u * 80;
    *(float4*)&sh.ct[u][k4 * 4] = *(const float4*)&c_ws[u * DI + k0 + k4 * 4];
  }
  __syncthreads();

  const int c = threadIdx.x & 63, s = threadIdx.x >> 6;
  const int col = blockIdx.x * 64 + c;              // 0..191
  const float* Wp = xpw + (size_t)(k0 + s * 80) * XD + col;

  float acc[U];
#pragma unroll
  for (int u = 0; u < U; ++u) acc[u] = 0.f;

  for (int kk = 0; kk < 80; kk += 4) {
    float w0 = Wp[(size_t)(kk + 0) * XD];
    float w1 = Wp[(size_t)(kk + 1) * XD];
    float w2 = Wp[(size_t)(kk + 2) * XD];
    float w3 = Wp[(size_t)(kk + 3) * XD];
#pragma unroll
    for (int u = 0; u < U; ++u) {
      float4 cv = *(const float4*)&sh.ct[u][s * 80 + kk];
      acc[u] = fmaf(cv.x, w0, acc[u]);
      acc[u] = fmaf(cv.y, w1, acc[u]);
      acc[u] = fmaf(cv.z, w2, acc[u]);
      acc[u] = fmaf(cv.w, w3, acc[u]);
    }
  }

  __syncthreads();
#pragma unroll
  for (int u = 0; u < U; ++u) sh.red[s][c][u] = acc[u];
  __syncthreads();

  for (int p = threadIdx.x; p < 64 * U; p += 256) {
    int cc = p & 63, u = p >> 6;
    float v = sh.red[0][cc][u] + sh.red[1][cc][u] + sh.red[2][cc][u] + sh.red[3][cc][u];
    atomicAdd(&x_dbl[u * XD + blockIdx.x * 64 + cc], v);
  }
}

// ---------------------------------------------------------------------------
// K3a: dt = softplus(x_dbl[:, :160] @ dt_proj_w + b).  grid 80, block 256.
// ---------------------------------------------------------------------------
__global__ __launch_bounds__(256) void k3a_dt(
    const float* __restrict__ x_dbl,
    const float* __restrict__ dpw, const float* __restrict__ dpb,
    float* __restrict__ dt_ws)
{
  __shared__ union { float xt[U][160]; float red[4][64][33]; } sh;

  for (int i4 = threadIdx.x; i4 < U * 40; i4 += 256) {
    int u = i4 / 40, r4 = i4 - u * 40;
    *(float4*)&sh.xt[u][r4 * 4] = *(const float4*)&x_dbl[u * XD + r4 * 4];
  }
  __syncthreads();

  const int c = threadIdx.x & 63, s = threadIdx.x >> 6;
  const int d = blockIdx.x * 64 + c;
  const float* Wp = dpw + (size_t)(s * 40) * DI + d;

  float acc[U];
#pragma unroll
  for (int u = 0; u < U; ++u) acc[u] = 0.f;

  for (int rr = 0; rr < 40; rr += 4) {
    float w0 = Wp[(size_t)(rr + 0) * DI];
    float w1 = Wp[(size_t)(rr + 1) * DI];
    float w2 = Wp[(size_t)(rr + 2) * DI];
    float w3 = Wp[(size_t)(rr + 3) * DI];
#pragma unroll
    for (int u = 0; u < U; ++u) {
      float4 xv = *(const float4*)&sh.xt[u][s * 40 + rr];
      acc[u] = fmaf(xv.x, w0, acc[u]);
      acc[u] = fmaf(xv.y, w1, acc[u]);
      acc[u] = fmaf(xv.z, w2, acc[u]);
      acc[u] = fmaf(xv.w, w3, acc[u]);
    }
  }

  __syncthreads();
#pragma unroll
  for (int u = 0; u < U; ++u) sh.red[s][c][u] = acc[u];
  __syncthreads();

  for (int p = threadIdx.x; p < 64 * U; p += 256) {
    int cc = p & 63, u = p >> 6;
    int dg = blockIdx.x * 64 + cc;
    float pre = sh.red[0][cc][u] + sh.red[1][cc][u] + sh.red[2][cc][u] + sh.red[3][cc][u]
              + dpb[dg];
    float dt = fmaxf(pre, 0.f) + log1pf(expf(-fabsf(pre)));   // softplus
    dt_ws[u * DI + dg] = dt;
  }
}

// ---------------------------------------------------------------------------
// K3b: elementwise SSM update + y = einsum + D*c, yr = y*res.  grid 640.
// ---------------------------------------------------------------------------
__global__ __launch_bounds__(256) void k3b_ssm(
    const float* __restrict__ x_dbl,
    const float* __restrict__ alog, const float* __restrict__ Dp,
    const float* __restrict__ ssm,
    const float* __restrict__ dt_ws,
    const float* __restrict__ c_ws, const float* __restrict__ res_ws,
    float* __restrict__ yr)
{
  const int i = blockIdx.x * 256 + threadIdx.x;   // [0, U*DI)
  const int u = i / DI, d = i - u * DI;

  const float dt = dt_ws[i];
  const float cv = c_ws[i];
  const float rv = res_ws[i];
  const float Dv = Dp[d];
  const float dtc = dt * cv;

  float4 B[4], C[4];
#pragma unroll
  for (int q = 0; q < 4; ++q) {
    B[q] = *(const float4*)&x_dbl[u * XD + RNK + q * 4];          // wave-uniform
    C[q] = *(const float4*)&x_dbl[u * XD + RNK + DS + q * 4];
  }

  const float* st = ssm + ((size_t)u * DI + d) * DS;
  float y = 0.f;
#pragma unroll
  for (int q = 0; q < 4; ++q) {
    float4 al = *(const float4*)&alog[d * DS + q * 4];
    float4 sv = *(const float4*)&st[q * 4];
    y += (sv.x * __expf(dt * -__expf(al.x)) + dtc * B[q].x) * C[q].x;
    y += (sv.y * __expf(dt * -__expf(al.y)) + dtc * B[q].y) * C[q].y;
    y += (sv.z * __expf(dt * -__expf(al.z)) + dtc * B[q].z) * C[q].z;
    y += (sv.w * __expf(dt * -__expf(al.w)) + dtc * B[q].w) * C[q].w;
  }
  y = fmaf(Dv, cv, y);
  yr[i] = y * rv;
}

// ---------------------------------------------------------------------------
// K5: out = sum of 64 K4 partials.  grid 320, block 256.
// ---------------------------------------------------------------------------
__global__ __launch_bounds__(256) void k5_reduce(
    const float* __restrict__ part4,
    float* __restrict__ out)
{
  const int i = blockIdx.x * 256 + threadIdx.x;   // [0, U*DM)
  const int u = i / DM, d = i - u * DM;
  float v = 0.f;
#pragma unroll
  for (int kc = 0; kc < 64; ++kc) v += part4[((size_t)kc * U + u) * DM + d];
  out[i] = v;
}

// ---------------------------------------------------------------------------
extern "C" void kernel_launch(void* const* d_in, const int* in_sizes, int n_in,
                              void* d_out, int out_size, void* d_ws, size_t ws_size,
                              hipStream_t stream)
{
  const float* x    = (const float*)d_in[0];
  const float* wssm = (const float*)d_in[1];
  const float* wmlp = (const float*)d_in[2];
  const float* wout = (const float*)d_in[3];
  const float* cw   = (const float*)d_in[4];
  const float* cb   = (const float*)d_in[5];
  const float* cs1  = (const float*)d_in[6];
  const float* cs2  = (const float*)d_in[7];
  const float* cs3  = (const float*)d_in[8];
  const float* xpw  = (const float*)d_in[9];
  const float* dpw  = (const float*)d_in[10];
  const float* dpb  = (const float*)d_in[11];
  const float* alog = (const float*)d_in[12];
  const float* Dp   = (const float*)d_in[13];
  const float* ssm  = (const float*)d_in[14];
  float* out = (float*)d_out;
  float* ws  = (float*)d_ws;

  float* part1  = ws;                               // 2*16*32*5120 = 5,242,880
  float* part4  = part1;                            // alias: K4 runs after K2a
  float* c_ws   = part1  + (size_t)2 * 16 * U * DI;
  float* res_ws = c_ws   + (size_t)U * DI;
  float* dt_ws  = res_ws + (size_t)U * DI;
  float* yrb    = dt_ws  + (size_t)U * DI;
  float* x_dbl  = yrb    + (size_t)U * DI;          // 6144 floats

  (void)hipMemsetAsync(x_dbl, 0, (size_t)U * XD * sizeof(float), stream);

  // K1: xs/res = xb @ {w_in_ssm, w_in_mlp}. grid (5120/256, 2560/160, 2)
  skinny_gemm<DI, 40><<<dim3(20, 16, 2), 256, 0, stream>>>(x, DM, wssm, wmlp, part1);
  k2a_convsilu<<<640, 256, 0, stream>>>(part1, cs1, cs2, cs3, cw, cb, c_ws, res_ws);
  k2b_xproj<<<dim3(3, 16), 256, 0, stream>>>(c_ws, xpw, x_dbl);
  k3a_dt<<<80, 256, 0, stream>>>(x_dbl, dpw, dpb, dt_ws);
  k3b_ssm<<<640, 256, 0, stream>>>(x_dbl, alog, Dp, ssm, dt_ws, c_ws, res_ws, yrb);
  // K4: out_part = yr @ w_out. grid (2560/256, 5120/80, 1)
  skinny_gemm<DM, 20><<<dim3(10, 64, 1), 256, 0, stream>>>(yrb, DI, wout, wout, part4);
  k5_reduce<<<320, 256, 0, stream>>>(part4, out);
}

// Round 5
// 102.838 us; speedup vs baseline: 1.6562x; 1.3983x over previous
//
#include <hip/hip_runtime.h>
#include <cstdint>
#include <cstddef>

#define U   32
#define DM  2560
#define DI  5120
#define DS  16
#define RNK 160
#define XD  192   // RNK + 2*DS

typedef __attribute__((ext_vector_type(8)))  short bf16x8;
typedef __attribute__((ext_vector_type(16))) float f32x16;

__device__ __forceinline__ unsigned int f2bf(float f) {
  union { float f; unsigned int u; } v; v.f = f;
  unsigned int r = v.u + 0x7FFFu + ((v.u >> 16) & 1u);   // RNE
  return r >> 16;
}

// ---------------------------------------------------------------------------
// MFMA skinny GEMM: part[kc][32][LDW] = A[32 x CHUNK] @ W[k0..k0+CHUNK][LDW]
// block 256 = 4 waves; wave w owns 32-col tile; one 32x32x16 MFMA per K-step.
// A staged to LDS in fragment order (bf16); B loaded per-lane from fp32 W.
// grid (LDW/128, K/CHUNK, nz).
// ---------------------------------------------------------------------------
template<int LDW, int CHUNK>
__global__ __launch_bounds__(256, 2) void skinny_mfma(
    const float* __restrict__ A, int lda,
    const float* __restrict__ W0, const float* __restrict__ W1,
    float* __restrict__ part)
{
  constexpr int NS = CHUNK / 16;
  __shared__ unsigned int albuf[NS][64][4];   // [k-step][lane][16B bf16x8]

  const int kcb = blockIdx.y, z = blockIdx.z;
  const int k0  = kcb * CHUNK;
  const float* W = z ? W1 : W0;

  // stage A chunk -> LDS in MFMA A-fragment order:
  // element (u,k): ks=k>>4, slot=(u&31)+32*((k>>3)&1), dword=(k>>1)&3
  for (int i = threadIdx.x; i < U * (CHUNK / 2); i += 256) {
    int u = i / (CHUNK / 2), p = i - u * (CHUNK / 2);
    int k = 2 * p;
    float2 v = *(const float2*)&A[(size_t)u * lda + k0 + k];
    albuf[k >> 4][(u & 31) + 32 * ((k >> 3) & 1)][(k >> 1) & 3] =
        f2bf(v.x) | (f2bf(v.y) << 16);
  }
  __syncthreads();

  const int lane = threadIdx.x & 63, w = threadIdx.x >> 6;
  const int half = lane >> 5, cl = lane & 31;
  const int col0 = blockIdx.x * 128 + w * 32;

  // B pointer: rows k0 + half*8 + j, col col0+cl
  const float* bp = W + (size_t)(k0 + half * 8) * LDW + col0 + cl;

  f32x16 acc{};
  float cur[8], nxt[8] = {};
#pragma unroll
  for (int j = 0; j < 8; ++j) cur[j] = bp[(size_t)j * LDW];

  for (int ks = 0; ks < NS; ++ks) {
    const float* bpn = bp + (size_t)16 * LDW;
    if (ks + 1 < NS) {
#pragma unroll
      for (int j = 0; j < 8; ++j) nxt[j] = bpn[(size_t)j * LDW];
    }
    union { bf16x8 v; unsigned short s[8]; } bu;
#pragma unroll
    for (int j = 0; j < 8; ++j) bu.s[j] = (unsigned short)f2bf(cur[j]);
    bf16x8 af = *(const bf16x8*)&albuf[ks][lane][0];
    acc = __builtin_amdgcn_mfma_f32_32x32x16_bf16(af, bu.v, acc, 0, 0, 0);
    bp = bpn;
#pragma unroll
    for (int j = 0; j < 8; ++j) cur[j] = nxt[j];
  }

  // D layout: col = lane&31, row m = (r&3) + 8*(r>>2) + 4*half
  const size_t zoff = (size_t)z * gridDim.y * U * LDW;
  float* po = part + zoff + ((size_t)kcb * U) * LDW + col0 + cl;
#pragma unroll
  for (int r = 0; r < 16; ++r) {
    int m = (r & 3) + 8 * (r >> 2) + 4 * half;
    po[(size_t)m * LDW] = acc[r];
  }
}

// ---------------------------------------------------------------------------
// K2a: reduce K1 partials (8 per z) + conv + silu.  grid 640, block 256.
// ---------------------------------------------------------------------------
__global__ __launch_bounds__(256) void k2a_convsilu(
    const float* __restrict__ part,
    const float* __restrict__ cs1, const float* __restrict__ cs2,
    const float* __restrict__ cs3,
    const float* __restrict__ cw,  const float* __restrict__ cb,
    float* __restrict__ c_ws, float* __restrict__ res_ws)
{
  const int i = blockIdx.x * 256 + threadIdx.x;   // [0, U*DI)
  const int u = i / DI, d = i - u * DI;
  float xs = 0.f, rs = 0.f;
#pragma unroll
  for (int kc = 0; kc < 8; ++kc) {
    xs += part[((size_t)kc * U       + u) * DI + d];
    rs += part[((size_t)(8 + kc) * U + u) * DI + d];
  }
  float cc = cs1[i] * cw[d] + cs2[i] * cw[DI + d] + cs3[i] * cw[2 * DI + d]
           + xs * cw[3 * DI + d] + cb[d];
  cc = cc / (1.f + __expf(-cc));                  // silu
  c_ws[i]   = cc;
  res_ws[i] = rs;
}

// ---------------------------------------------------------------------------
// K2b: x_dbl = c @ x_proj_w (32x5120 @ 5120x192).  grid (3, 16), block 256.
// ---------------------------------------------------------------------------
__global__ __launch_bounds__(256) void k2b_xproj(
    const float* __restrict__ c_ws,
    const float* __restrict__ xpw,
    float* __restrict__ x_dbl)
{
  __shared__ union { float ct[U][320]; float red[4][64][33]; } sh;
  const int k0 = blockIdx.y * 320;

  for (int i4 = threadIdx.x; i4 < U * 80; i4 += 256) {
    int u = i4 / 80, k4 = i4 - u * 80;
    *(float4*)&sh.ct[u][k4 * 4] = *(const float4*)&c_ws[u * DI + k0 + k4 * 4];
  }
  __syncthreads();

  const int c = threadIdx.x & 63, s = threadIdx.x >> 6;
  const int col = blockIdx.x * 64 + c;              // 0..191
  const float* Wp = xpw + (size_t)(k0 + s * 80) * XD + col;

  float acc[U];
#pragma unroll
  for (int u = 0; u < U; ++u) acc[u] = 0.f;

  for (int kk = 0; kk < 80; kk += 4) {
    float w0 = Wp[(size_t)(kk + 0) * XD];
    float w1 = Wp[(size_t)(kk + 1) * XD];
    float w2 = Wp[(size_t)(kk + 2) * XD];
    float w3 = Wp[(size_t)(kk + 3) * XD];
#pragma unroll
    for (int u = 0; u < U; ++u) {
      float4 cv = *(const float4*)&sh.ct[u][s * 80 + kk];
      acc[u] = fmaf(cv.x, w0, acc[u]);
      acc[u] = fmaf(cv.y, w1, acc[u]);
      acc[u] = fmaf(cv.z, w2, acc[u]);
      acc[u] = fmaf(cv.w, w3, acc[u]);
    }
  }

  __syncthreads();
#pragma unroll
  for (int u = 0; u < U; ++u) sh.red[s][c][u] = acc[u];
  __syncthreads();

  for (int p = threadIdx.x; p < 64 * U; p += 256) {
    int cc = p & 63, u = p >> 6;
    float v = sh.red[0][cc][u] + sh.red[1][cc][u] + sh.red[2][cc][u] + sh.red[3][cc][u];
    atomicAdd(&x_dbl[u * XD + blockIdx.x * 64 + cc], v);
  }
}

// ---------------------------------------------------------------------------
// K3a: dt = softplus(x_dbl[:, :160] @ dt_proj_w + b).  grid 80, block 256.
// ---------------------------------------------------------------------------
__global__ __launch_bounds__(256) void k3a_dt(
    const float* __restrict__ x_dbl,
    const float* __restrict__ dpw, const float* __restrict__ dpb,
    float* __restrict__ dt_ws)
{
  __shared__ union { float xt[U][160]; float red[4][64][33]; } sh;

  for (int i4 = threadIdx.x; i4 < U * 40; i4 += 256) {
    int u = i4 / 40, r4 = i4 - u * 40;
    *(float4*)&sh.xt[u][r4 * 4] = *(const float4*)&x_dbl[u * XD + r4 * 4];
  }
  __syncthreads();

  const int c = threadIdx.x & 63, s = threadIdx.x >> 6;
  const int d = blockIdx.x * 64 + c;
  const float* Wp = dpw + (size_t)(s * 40) * DI + d;

  float acc[U];
#pragma unroll
  for (int u = 0; u < U; ++u) acc[u] = 0.f;

  for (int rr = 0; rr < 40; rr += 4) {
    float w0 = Wp[(size_t)(rr + 0) * DI];
    float w1 = Wp[(size_t)(rr + 1) * DI];
    float w2 = Wp[(size_t)(rr + 2) * DI];
    float w3 = Wp[(size_t)(rr + 3) * DI];
#pragma unroll
    for (int u = 0; u < U; ++u) {
      float4 xv = *(const float4*)&sh.xt[u][s * 40 + rr];
      acc[u] = fmaf(xv.x, w0, acc[u]);
      acc[u] = fmaf(xv.y, w1, acc[u]);
      acc[u] = fmaf(xv.z, w2, acc[u]);
      acc[u] = fmaf(xv.w, w3, acc[u]);
    }
  }

  __syncthreads();
#pragma unroll
  for (int u = 0; u < U; ++u) sh.red[s][c][u] = acc[u];
  __syncthreads();

  for (int p = threadIdx.x; p < 64 * U; p += 256) {
    int cc = p & 63, u = p >> 6;
    int dg = blockIdx.x * 64 + cc;
    float pre = sh.red[0][cc][u] + sh.red[1][cc][u] + sh.red[2][cc][u] + sh.red[3][cc][u]
              + dpb[dg];
    float dt = fmaxf(pre, 0.f) + log1pf(expf(-fabsf(pre)));   // softplus
    dt_ws[u * DI + dg] = dt;
  }
}

// ---------------------------------------------------------------------------
// K3b: elementwise SSM update + y = einsum + D*c, yr = y*res.  grid 640.
// ---------------------------------------------------------------------------
__global__ __launch_bounds__(256) void k3b_ssm(
    const float* __restrict__ x_dbl,
    const float* __restrict__ alog, const float* __restrict__ Dp,
    const float* __restrict__ ssm,
    const float* __restrict__ dt_ws,
    const float* __restrict__ c_ws, const float* __restrict__ res_ws,
    float* __restrict__ yr)
{
  const int i = blockIdx.x * 256 + threadIdx.x;   // [0, U*DI)
  const int u = i / DI, d = i - u * DI;

  const float dt = dt_ws[i];
  const float cv = c_ws[i];
  const float rv = res_ws[i];
  const float Dv = Dp[d];
  const float dtc = dt * cv;

  float4 B[4], C[4];
#pragma unroll
  for (int q = 0; q < 4; ++q) {
    B[q] = *(const float4*)&x_dbl[u * XD + RNK + q * 4];          // wave-uniform
    C[q] = *(const float4*)&x_dbl[u * XD + RNK + DS + q * 4];
  }

  const float* st = ssm + ((size_t)u * DI + d) * DS;
  float y = 0.f;
#pragma unroll
  for (int q = 0; q < 4; ++q) {
    float4 al = *(const float4*)&alog[d * DS + q * 4];
    float4 sv = *(const float4*)&st[q * 4];
    y += (sv.x * __expf(dt * -__expf(al.x)) + dtc * B[q].x) * C[q].x;
    y += (sv.y * __expf(dt * -__expf(al.y)) + dtc * B[q].y) * C[q].y;
    y += (sv.z * __expf(dt * -__expf(al.z)) + dtc * B[q].z) * C[q].z;
    y += (sv.w * __expf(dt * -__expf(al.w)) + dtc * B[q].w) * C[q].w;
  }
  y = fmaf(Dv, cv, y);
  yr[i] = y * rv;
}

// ---------------------------------------------------------------------------
// K5: out = sum of 32 K4 partials.  grid 320, block 256.
// ---------------------------------------------------------------------------
__global__ __launch_bounds__(256) void k5_reduce(
    const float* __restrict__ part4,
    float* __restrict__ out)
{
  const int i = blockIdx.x * 256 + threadIdx.x;   // [0, U*DM)
  const int u = i / DM, d = i - u * DM;
  float v = 0.f;
#pragma unroll
  for (int kc = 0; kc < 32; ++kc) v += part4[((size_t)kc * U + u) * DM + d];
  out[i] = v;
}

// ---------------------------------------------------------------------------
extern "C" void kernel_launch(void* const* d_in, const int* in_sizes, int n_in,
                              void* d_out, int out_size, void* d_ws, size_t ws_size,
                              hipStream_t stream)
{
  const float* x    = (const float*)d_in[0];
  const float* wssm = (const float*)d_in[1];
  const float* wmlp = (const float*)d_in[2];
  const float* wout = (const float*)d_in[3];
  const float* cw   = (const float*)d_in[4];
  const float* cb   = (const float*)d_in[5];
  const float* cs1  = (const float*)d_in[6];
  const float* cs2  = (const float*)d_in[7];
  const float* cs3  = (const float*)d_in[8];
  const float* xpw  = (const float*)d_in[9];
  const float* dpw  = (const float*)d_in[10];
  const float* dpb  = (const float*)d_in[11];
  const float* alog = (const float*)d_in[12];
  const float* Dp   = (const float*)d_in[13];
  const float* ssm  = (const float*)d_in[14];
  float* out = (float*)d_out;
  float* ws  = (float*)d_ws;

  float* part1  = ws;                               // 2*8*32*5120 = 2,621,440
  float* part4  = part1;                            // alias: 32*32*2560 same size
  float* c_ws   = part1  + (size_t)2 * 8 * U * DI;
  float* res_ws = c_ws   + (size_t)U * DI;
  float* dt_ws  = res_ws + (size_t)U * DI;
  float* yrb    = dt_ws  + (size_t)U * DI;
  float* x_dbl  = yrb    + (size_t)U * DI;          // 6144 floats

  (void)hipMemsetAsync(x_dbl, 0, (size_t)U * XD * sizeof(float), stream);

  // K1: xs/res = xb @ {w_in_ssm, w_in_mlp}. 128 cols/block, CHUNK=320.
  skinny_mfma<DI, 320><<<dim3(40, 8, 2), 256, 0, stream>>>(x, DM, wssm, wmlp, part1);
  k2a_convsilu<<<640, 256, 0, stream>>>(part1, cs1, cs2, cs3, cw, cb, c_ws, res_ws);
  k2b_xproj<<<dim3(3, 16), 256, 0, stream>>>(c_ws, xpw, x_dbl);
  k3a_dt<<<80, 256, 0, stream>>>(x_dbl, dpw, dpb, dt_ws);
  k3b_ssm<<<640, 256, 0, stream>>>(x_dbl, alog, Dp, ssm, dt_ws, c_ws, res_ws, yrb);
  // K4: out_part = yr @ w_out. 128 cols/block, CHUNK=160.
  skinny_mfma<DM, 160><<<dim3(20, 32, 1), 256, 0, stream>>>(yrb, DI, wout, wout, part4);
  k5_reduce<<<320, 256, 0, stream>>>(part4, out);
}

// Round 6
// 84.974 us; speedup vs baseline: 2.0044x; 1.2102x over previous
//
#include <hip/hip_runtime.h>
#include <hip/hip_bf16.h>
#include <cstdint>
#include <cstddef>

#define U   32
#define DM  2560
#define DI  5120
#define DS  16
#define RNK 160
#define XD  192   // RNK + 2*DS
#define KC1 20    // K1 k-slices (CHUNK 128)
#define KC4 80    // K4 k-slices (CHUNK 64)

typedef __attribute__((ext_vector_type(8)))  short bf16x8;
typedef __attribute__((ext_vector_type(16))) float f32x16;

__device__ __forceinline__ unsigned int pkbf(float a, float b) {
  __hip_bfloat162 h = __float22bfloat162_rn(make_float2(a, b));
  union { __hip_bfloat162 h; unsigned int u; } v; v.h = h; return v.u;
}
__device__ __forceinline__ unsigned short f2bfu(float f) {
  __hip_bfloat16 h = __float2bfloat16(f);
  union { __hip_bfloat16 h; unsigned short u; } v; v.h = h; return v.u;
}
__device__ __forceinline__ float bf2f(unsigned int s) {
  union { float f; unsigned int u; } v; v.u = s << 16; return v.f;
}

// ---------------------------------------------------------------------------
// MFMA skinny GEMM v3: bf16 partials part[z][kc][32][LDW] = A[32xCHUNK] @ W.
// block 256 = 4 waves, 256 cols/block (wave w: cols w*64..w*64+63, 2 frags).
// Per 16-row round: block stages W 16x256 via FULL-1KB-contiguous wave loads
// (thread owns row-pair, 4 cols -> packs bf16 k-pair dwords), LDS [k2][256],
// conflict-free; then 2 MFMA 32x32x16 per wave. 2 barriers/round.
// ---------------------------------------------------------------------------
template<int LDW, int CHUNK>
__global__ __launch_bounds__(256, 4) void skinny_mfma(
    const float* __restrict__ A, int lda,
    const float* __restrict__ W0, const float* __restrict__ W1,
    unsigned short* __restrict__ part)
{
  constexpr int NS = CHUNK / 16;
  __shared__ unsigned int albuf[NS][65][4];   // A frags, +65 pad: no conflicts
  __shared__ unsigned int bbuf[8][256];       // [k2][col] bf16-pair dwords

  const int tid = threadIdx.x;
  const int kcb = blockIdx.y, z = blockIdx.z;
  const int k0  = kcb * CHUNK;
  const float* __restrict__ W = z ? W1 : W0;
  const int col0 = blockIdx.x * 256;

  // ---- stage A panel [32][CHUNK] -> bf16 MFMA-A fragment order
  for (int i = tid; i < U * (CHUNK / 2); i += 256) {
    const int u  = i / (CHUNK / 2);
    const int kp = i - u * (CHUNK / 2);
    const int k  = 2 * kp;
    const float2 v = *(const float2*)&A[(size_t)u * lda + k0 + k];
    albuf[k >> 4][u + U * ((k >> 3) & 1)][(k >> 1) & 3] = pkbf(v.x, v.y);
  }

  const int c4 = (tid & 63) * 4;    // col group within block tile
  const int rp = tid >> 6;          // row-pair 0..3
  const float* __restrict__ wb = W + ((size_t)k0 + 2 * rp) * LDW + col0 + c4;

  const int lane = tid & 63, w = tid >> 6;
  const int cl = lane & 31, half = lane >> 5;
  const int bcol = w * 64 + cl;

  f32x16 acc0{}, acc1{};

  // prologue: round 0 loads (each wave-instr = one contiguous 1KB row segment)
  float4 r0 = *(const float4*)(wb);
  float4 r1 = *(const float4*)(wb + LDW);
  float4 r2 = *(const float4*)(wb + (size_t)8 * LDW);
  float4 r3 = *(const float4*)(wb + (size_t)9 * LDW);

#pragma unroll
  for (int ks = 0; ks < NS; ++ks) {
    // pack current 16x256 tile -> LDS (b128 writes, conflict-free)
    uint4 dA, dB;
    dA.x = pkbf(r0.x, r1.x); dA.y = pkbf(r0.y, r1.y);
    dA.z = pkbf(r0.z, r1.z); dA.w = pkbf(r0.w, r1.w);
    dB.x = pkbf(r2.x, r3.x); dB.y = pkbf(r2.y, r3.y);
    dB.z = pkbf(r2.z, r3.z); dB.w = pkbf(r2.w, r3.w);
    *(uint4*)&bbuf[rp][c4]     = dA;
    *(uint4*)&bbuf[rp + 4][c4] = dB;
    if (ks + 1 < NS) {
      const float* wn = wb + (size_t)(ks + 1) * 16 * LDW;
      r0 = *(const float4*)(wn);
      r1 = *(const float4*)(wn + LDW);
      r2 = *(const float4*)(wn + (size_t)8 * LDW);
      r3 = *(const float4*)(wn + (size_t)9 * LDW);
    }
    __syncthreads();
    bf16x8 af = *(const bf16x8*)&albuf[ks][lane][0];
    union { bf16x8 v; unsigned int d[4]; } b0, b1;
#pragma unroll
    for (int q = 0; q < 4; ++q) {
      b0.d[q] = bbuf[half * 4 + q][bcol];
      b1.d[q] = bbuf[half * 4 + q][bcol + 32];
    }
    acc0 = __builtin_amdgcn_mfma_f32_32x32x16_bf16(af, b0.v, acc0, 0, 0, 0);
    acc1 = __builtin_amdgcn_mfma_f32_32x32x16_bf16(af, b1.v, acc1, 0, 0, 0);
    __syncthreads();
  }

  // ---- epilogue: D (col=lane&31, row=(r&3)+8*(r>>2)+4*half) -> bf16 partials
  unsigned short* po = part + (size_t)(z * gridDim.y + kcb) * U * LDW + col0;
#pragma unroll
  for (int f = 0; f < 2; ++f) {
    const int gc = w * 64 + f * 32 + cl;
    const f32x16& a = f ? acc1 : acc0;
#pragma unroll
    for (int r = 0; r < 16; ++r) {
      const int m = (r & 3) + 8 * (r >> 2) + 4 * half;
      po[(size_t)m * LDW + gc] = f2bfu(a[r]);
    }
  }
}

// ---------------------------------------------------------------------------
// K2a: reduce K1 bf16 partials (KC1 per z) + conv + silu. 2 elems/thread.
// grid 320, block 256.
// ---------------------------------------------------------------------------
__global__ __launch_bounds__(256) void k2a_convsilu(
    const unsigned short* __restrict__ part,
    const float* __restrict__ cs1, const float* __restrict__ cs2,
    const float* __restrict__ cs3,
    const float* __restrict__ cw,  const float* __restrict__ cb,
    float* __restrict__ c_ws, float* __restrict__ res_ws)
{
  const int t = blockIdx.x * 256 + threadIdx.x;   // [0, U*DI/2)
  const int i = 2 * t;
  const int u = i / DI, d = i - u * DI;
  float xs0 = 0.f, xs1 = 0.f, rs0 = 0.f, rs1 = 0.f;
#pragma unroll 4
  for (int kc = 0; kc < KC1; ++kc) {
    unsigned int a = *(const unsigned int*)&part[((size_t)kc * U + u) * DI + d];
    unsigned int b = *(const unsigned int*)&part[((size_t)(KC1 + kc) * U + u) * DI + d];
    xs0 += bf2f(a & 0xffffu); xs1 += bf2f(a >> 16);
    rs0 += bf2f(b & 0xffffu); rs1 += bf2f(b >> 16);
  }
  const float2 s1 = *(const float2*)&cs1[i];
  const float2 s2 = *(const float2*)&cs2[i];
  const float2 s3 = *(const float2*)&cs3[i];
  const float2 w0 = *(const float2*)&cw[d];
  const float2 w1 = *(const float2*)&cw[DI + d];
  const float2 w2 = *(const float2*)&cw[2 * DI + d];
  const float2 w3 = *(const float2*)&cw[3 * DI + d];
  const float2 bb = *(const float2*)&cb[d];
  float c0 = s1.x * w0.x + s2.x * w1.x + s3.x * w2.x + xs0 * w3.x + bb.x;
  float c1 = s1.y * w0.y + s2.y * w1.y + s3.y * w2.y + xs1 * w3.y + bb.y;
  c0 = c0 / (1.f + __expf(-c0));
  c1 = c1 / (1.f + __expf(-c1));
  *(float2*)&c_ws[i]   = make_float2(c0, c1);
  *(float2*)&res_ws[i] = make_float2(rs0, rs1);
}

// ---------------------------------------------------------------------------
// K2b: x_dbl = c @ x_proj_w (32x5120 @ 5120x192).  grid (3, 64), block 256.
// K-chunk 80; wave owns 20-row slice; LDS reduce; atomics (64/addr).
// ---------------------------------------------------------------------------
__global__ __launch_bounds__(256) void k2b_xproj(
    const float* __restrict__ c_ws,
    const float* __restrict__ xpw,
    float* __restrict__ x_dbl)
{
  __shared__ union { float ct[U][80]; float red[4][64][33]; } sh;
  const int k0 = blockIdx.y * 80;

  for (int i4 = threadIdx.x; i4 < U * 20; i4 += 256) {
    int u = i4 / 20, k4 = i4 - u * 20;
    *(float4*)&sh.ct[u][k4 * 4] = *(const float4*)&c_ws[u * DI + k0 + k4 * 4];
  }
  __syncthreads();

  const int c = threadIdx.x & 63, s = threadIdx.x >> 6;
  const int col = blockIdx.x * 64 + c;              // 0..191
  const float* Wp = xpw + (size_t)(k0 + s * 20) * XD + col;

  float acc[U];
#pragma unroll
  for (int u = 0; u < U; ++u) acc[u] = 0.f;

  for (int kk = 0; kk < 20; kk += 4) {
    float w0 = Wp[(size_t)(kk + 0) * XD];
    float w1 = Wp[(size_t)(kk + 1) * XD];
    float w2 = Wp[(size_t)(kk + 2) * XD];
    float w3 = Wp[(size_t)(kk + 3) * XD];
#pragma unroll
    for (int u = 0; u < U; ++u) {
      float4 cv = *(const float4*)&sh.ct[u][s * 20 + kk];
      acc[u] = fmaf(cv.x, w0, acc[u]);
      acc[u] = fmaf(cv.y, w1, acc[u]);
      acc[u] = fmaf(cv.z, w2, acc[u]);
      acc[u] = fmaf(cv.w, w3, acc[u]);
    }
  }

  __syncthreads();
#pragma unroll
  for (int u = 0; u < U; ++u) sh.red[s][c][u] = acc[u];
  __syncthreads();

  for (int p = threadIdx.x; p < 64 * U; p += 256) {
    int cc = p & 63, u = p >> 6;
    float v = sh.red[0][cc][u] + sh.red[1][cc][u] + sh.red[2][cc][u] + sh.red[3][cc][u];
    atomicAdd(&x_dbl[u * XD + blockIdx.x * 64 + cc], v);
  }
}

// ---------------------------------------------------------------------------
// K3a: dt = softplus(x_dbl[:, :160] @ dt_proj_w + b).  grid 80, block 256.
// ---------------------------------------------------------------------------
__global__ __launch_bounds__(256) void k3a_dt(
    const float* __restrict__ x_dbl,
    const float* __restrict__ dpw, const float* __restrict__ dpb,
    float* __restrict__ dt_ws)
{
  __shared__ union { float xt[U][160]; float red[4][64][33]; } sh;

  for (int i4 = threadIdx.x; i4 < U * 40; i4 += 256) {
    int u = i4 / 40, r4 = i4 - u * 40;
    *(float4*)&sh.xt[u][r4 * 4] = *(const float4*)&x_dbl[u * XD + r4 * 4];
  }
  __syncthreads();

  const int c = threadIdx.x & 63, s = threadIdx.x >> 6;
  const int d = blockIdx.x * 64 + c;
  const float* Wp = dpw + (size_t)(s * 40) * DI + d;

  float acc[U];
#pragma unroll
  for (int u = 0; u < U; ++u) acc[u] = 0.f;

  for (int rr = 0; rr < 40; rr += 4) {
    float w0 = Wp[(size_t)(rr + 0) * DI];
    float w1 = Wp[(size_t)(rr + 1) * DI];
    float w2 = Wp[(size_t)(rr + 2) * DI];
    float w3 = Wp[(size_t)(rr + 3) * DI];
#pragma unroll
    for (int u = 0; u < U; ++u) {
      float4 xv = *(const float4*)&sh.xt[u][s * 40 + rr];
      acc[u] = fmaf(xv.x, w0, acc[u]);
      acc[u] = fmaf(xv.y, w1, acc[u]);
      acc[u] = fmaf(xv.z, w2, acc[u]);
      acc[u] = fmaf(xv.w, w3, acc[u]);
    }
  }

  __syncthreads();
#pragma unroll
  for (int u = 0; u < U; ++u) sh.red[s][c][u] = acc[u];
  __syncthreads();

  for (int p = threadIdx.x; p < 64 * U; p += 256) {
    int cc = p & 63, u = p >> 6;
    int dg = blockIdx.x * 64 + cc;
    float pre = sh.red[0][cc][u] + sh.red[1][cc][u] + sh.red[2][cc][u] + sh.red[3][cc][u]
              + dpb[dg];
    float dt = fmaxf(pre, 0.f) + log1pf(expf(-fabsf(pre)));   // softplus
    dt_ws[u * DI + dg] = dt;
  }
}

// ---------------------------------------------------------------------------
// K3b: elementwise SSM update + y = einsum + D*c, yr = y*res.  grid 640.
// ---------------------------------------------------------------------------
__global__ __launch_bounds__(256) void k3b_ssm(
    const float* __restrict__ x_dbl,
    const float* __restrict__ alog, const float* __restrict__ Dp,
    const float* __restrict__ ssm,
    const float* __restrict__ dt_ws,
    const float* __restrict__ c_ws, const float* __restrict__ res_ws,
    float* __restrict__ yr)
{
  const int i = blockIdx.x * 256 + threadIdx.x;   // [0, U*DI)
  const int u = i / DI, d = i - u * DI;

  const float dt = dt_ws[i];
  const float cv = c_ws[i];
  const float rv = res_ws[i];
  const float Dv = Dp[d];
  const float dtc = dt * cv;

  float4 B[4], C[4];
#pragma unroll
  for (int q = 0; q < 4; ++q) {
    B[q] = *(const float4*)&x_dbl[u * XD + RNK + q * 4];          // wave-uniform
    C[q] = *(const float4*)&x_dbl[u * XD + RNK + DS + q * 4];
  }

  const float* st = ssm + ((size_t)u * DI + d) * DS;
  float y = 0.f;
#pragma unroll
  for (int q = 0; q < 4; ++q) {
    float4 al = *(const float4*)&alog[d * DS + q * 4];
    float4 sv = *(const float4*)&st[q * 4];
    y += (sv.x * __expf(dt * -__expf(al.x)) + dtc * B[q].x) * C[q].x;
    y += (sv.y * __expf(dt * -__expf(al.y)) + dtc * B[q].y) * C[q].y;
    y += (sv.z * __expf(dt * -__expf(al.z)) + dtc * B[q].z) * C[q].z;
    y += (sv.w * __expf(dt * -__expf(al.w)) + dtc * B[q].w) * C[q].w;
  }
  y = fmaf(Dv, cv, y);
  yr[i] = y * rv;
}

// ---------------------------------------------------------------------------
// K5: out = sum of KC4 bf16 K4 partials.  2 elems/thread.  grid 160.
// ---------------------------------------------------------------------------
__global__ __launch_bounds__(256) void k5_reduce(
    const unsigned short* __restrict__ part4,
    float* __restrict__ out)
{
  const int t = blockIdx.x * 256 + threadIdx.x;   // [0, U*DM/2)
  const int i = 2 * t;
  const int u = i / DM, d = i - u * DM;
  float v0 = 0.f, v1 = 0.f;
#pragma unroll 8
  for (int kc = 0; kc < KC4; ++kc) {
    unsigned int a = *(const unsigned int*)&part4[((size_t)kc * U + u) * DM + d];
    v0 += bf2f(a & 0xffffu);
    v1 += bf2f(a >> 16);
  }
  *(float2*)&out[i] = make_float2(v0, v1);
}

// ---------------------------------------------------------------------------
extern "C" void kernel_launch(void* const* d_in, const int* in_sizes, int n_in,
                              void* d_out, int out_size, void* d_ws, size_t ws_size,
                              hipStream_t stream)
{
  const float* x    = (const float*)d_in[0];
  const float* wssm = (const float*)d_in[1];
  const float* wmlp = (const float*)d_in[2];
  const float* wout = (const float*)d_in[3];
  const float* cw   = (const float*)d_in[4];
  const float* cb   = (const float*)d_in[5];
  const float* cs1  = (const float*)d_in[6];
  const float* cs2  = (const float*)d_in[7];
  const float* cs3  = (const float*)d_in[8];
  const float* xpw  = (const float*)d_in[9];
  const float* dpw  = (const float*)d_in[10];
  const float* dpb  = (const float*)d_in[11];
  const float* alog = (const float*)d_in[12];
  const float* Dp   = (const float*)d_in[13];
  const float* ssm  = (const float*)d_in[14];
  float* out = (float*)d_out;

  // workspace: bf16 partials (aliased K1/K4: both 6,553,600 ushorts), then fp32
  unsigned short* partb = (unsigned short*)d_ws;    // 2*KC1*32*DI == KC4*32*DM
  float* c_ws   = (float*)(partb + (size_t)2 * KC1 * U * DI);
  float* res_ws = c_ws   + (size_t)U * DI;
  float* dt_ws  = res_ws + (size_t)U * DI;
  float* yrb    = dt_ws  + (size_t)U * DI;
  float* x_dbl  = yrb    + (size_t)U * DI;          // 6144 floats

  (void)hipMemsetAsync(x_dbl, 0, (size_t)U * XD * sizeof(float), stream);

  // K1: xs/res = xb @ {w_in_ssm, w_in_mlp}. grid (5120/256, 2560/128, 2)
  skinny_mfma<DI, 128><<<dim3(20, KC1, 2), 256, 0, stream>>>(x, DM, wssm, wmlp, partb);
  k2a_convsilu<<<320, 256, 0, stream>>>(partb, cs1, cs2, cs3, cw, cb, c_ws, res_ws);
  k2b_xproj<<<dim3(3, 64), 256, 0, stream>>>(c_ws, xpw, x_dbl);
  k3a_dt<<<80, 256, 0, stream>>>(x_dbl, dpw, dpb, dt_ws);
  k3b_ssm<<<640, 256, 0, stream>>>(x_dbl, alog, Dp, ssm, dt_ws, c_ws, res_ws, yrb);
  // K4: out_part = yr @ w_out. grid (2560/256, 5120/64, 1)
  skinny_mfma<DM, 64><<<dim3(10, KC4, 1), 256, 0, stream>>>(yrb, DI, wout, wout, partb);
  k5_reduce<<<160, 256, 0, stream>>>(partb, out);
}